// Round 13
// baseline (52.901 us; speedup 1.0000x reference)
//
#include <hip/hip_runtime.h>
#include <math.h>
#include <stdint.h>

#define NB 16
#define NH 512
#define NW 512
#define PLANE (NH * NW)
#define INF2 1.0e18f   // == fl(1e9f*1e9f), matches reference d*d rounding
#define BIG 3.0e38f
#define NSEG 64        // 512 / 8
#define TWB 8          // w-tile width in k_h
#define HROW 516       // LDS row stride (floats)

// ---------------------------------------------------------------------------
// One 8-wide segment of the exact min-plus: best[j] = min(best[j],
// h[k] - 2*i_j*k). Exact ints < 2^24 on finite path -> bit-exact; INF2
// absorbs shifts (ulp(1e18) >> 2^20). min3-pair form.
// ---------------------------------------------------------------------------
__device__ __forceinline__ void eval_seg(const float* __restrict__ hrow,
                                         int ss, float* best,
                                         const float* neg2i) {
    const float* hp = hrow + ss * 8;
    float4 A = *reinterpret_cast<const float4*>(hp);
    float4 B = *reinterpret_cast<const float4*>(hp + 4);
    float s8f = (float)(ss * 8);
#pragma unroll
    for (int j = 0; j < 8; ++j) {
        float n2 = neg2i[j];
        float c0 = fmaf(n2, s8f, A.x);
        float c1 = fmaf(n2, s8f + 1.0f, A.y);
        float c2 = fmaf(n2, s8f + 2.0f, A.z);
        float c3 = fmaf(n2, s8f + 3.0f, A.w);
        float c4 = fmaf(n2, s8f + 4.0f, B.x);
        float c5 = fmaf(n2, s8f + 5.0f, B.y);
        float c6 = fmaf(n2, s8f + 6.0f, B.z);
        float c7 = fmaf(n2, s8f + 7.0f, B.w);
        float bb = fminf(fminf(best[j], c0), c1);
        bb = fminf(fminf(bb, c2), c3);
        bb = fminf(fminf(bb, c4), c5);
        bb = fminf(fminf(bb, c6), c7);
        best[j] = bb;
    }
}

__device__ __forceinline__ float bmax8(const float* best, const float* ifl) {
    float t0 = fmaf(ifl[0], ifl[0], best[0]);
    float t1 = fmaf(ifl[1], ifl[1], best[1]);
    float t2 = fmaf(ifl[2], ifl[2], best[2]);
    float t3 = fmaf(ifl[3], ifl[3], best[3]);
    float t4 = fmaf(ifl[4], ifl[4], best[4]);
    float t5 = fmaf(ifl[5], ifl[5], best[5]);
    float t6 = fmaf(ifl[6], ifl[6], best[6]);
    float t7 = fmaf(ifl[7], ifl[7], best[7]);
    float m = fmaxf(fmaxf(t0, t1), t2);
    m = fmaxf(fmaxf(m, t3), t4);
    m = fmaxf(fmaxf(m, t5), t6);
    return fmaxf(m, t7);
}

// ---------------------------------------------------------------------------
// Ring-pruned eval (R10, proven): true-space bmax; seg s at ring r skippable
// when gap^2 + min_seg(g) >= bmax, gap = 8(r-1)+1; break when gap^2 >= bmax.
// sminw stride TWB. Good for sparse (indicator) rows: all-INF rings prune
// instantly via smin.
// ---------------------------------------------------------------------------
__device__ __forceinline__ void eval_ring(const float* __restrict__ hrow,
                                          const float* __restrict__ sminw,
                                          int q, float* best,
                                          const float* neg2i,
                                          const float* ifl) {
    float bmax = BIG;
    for (int step = 0; step < 2 * NSEG - 1; ++step) {
        int r = (step + 1) >> 1;
        float gapf = (float)(8 * (r - 1) + 1);
        float gap2 = gapf * gapf;
        if ((step & 1) && gap2 >= bmax) break;
        int s = (step & 1) ? (q - r) : (q + r);
        if (s < 0 || s >= NSEG) continue;
        if (step && (gap2 + sminw[s * TWB] >= bmax)) continue;
        eval_seg(hrow, s, best, neg2i);
        bmax = bmax8(best, ifl);
    }
}

// ---------------------------------------------------------------------------
// Window eval (R11, proven): home+ring1 branch-free, then sqrt(bmax) window
// unconditionally. Superset of candidates contains argmin -> exact.
// Good for dense (post-H) rows: window is tiny.
// ---------------------------------------------------------------------------
__device__ __forceinline__ void eval_window(const float* __restrict__ hrow,
                                            int q, float* best,
                                            const float* neg2i,
                                            const float* ifl) {
    int s_lo0 = (q > 0) ? q - 1 : 0;
    int s_hi0 = (q < NSEG - 1) ? q + 1 : NSEG - 1;
    for (int ss = s_lo0; ss <= s_hi0; ++ss) eval_seg(hrow, ss, best, neg2i);
    float bmax = bmax8(best, ifl);
    int sw = (int)sqrtf(bmax) + 1;
    int i0 = q * 8;
    int s_lo = (i0 - sw) >> 3;
    int s_hi = (i0 + 7 + sw) >> 3;
    if (s_lo < 0) s_lo = 0;
    if (s_hi > NSEG - 1) s_hi = NSEG - 1;
    for (int ss = s_lo; ss <= s_hi; ++ss) {
        if (ss >= s_lo0 && ss <= s_hi0) continue;
        eval_seg(hrow, ss, best, neg2i);
    }
}

// ---------------------------------------------------------------------------
// K_h: FIRST pass = min-plus along H on the 0/INF indicator, read x directly.
// Block (w-tile 8, b); 512 thr. hs[w][k] = k^2 if x==0 else INF2. NaN flag
// recorded positionally. Output ws = fl(fl(i^2+best) + w^2) (w^2 folded for
// the W pass), NaN flag in sign bit. Grid (64, 16) = 1024 blocks.
// ---------------------------------------------------------------------------
__global__ __launch_bounds__(512, 4) void k_pass_h(const float* __restrict__ x,
                                                   float* __restrict__ ws) {
    __shared__ float hs[TWB * HROW];        // 16.1 KB
    __shared__ float smin[NSEG * TWB];      // 2 KB
    __shared__ unsigned int flgw[NH * 2];   // 4 KB (flag byte per (k,w))
    int t = threadIdx.x;
    int b = blockIdx.y;
    int w0 = blockIdx.x * TWB;
    const float* xb = x + (size_t)b * PLANE + w0;

    for (int m = t; m < 1024; m += 512) {
        int k = m >> 1;
        int half = m & 1;
        float4 v = *reinterpret_cast<const float4*>(xb + (size_t)k * NW + half * 4);
        float kk = (float)(k * k);
        unsigned int f = 0;
#pragma unroll
        for (int e = 0; e < 4; ++e) {
            float val = (&v.x)[e];
            int w = half * 4 + e;
            hs[w * HROW + k] = (val == 0.0f) ? kk : INF2;  // NaN != 0 -> fg
            f |= (isnan(val) ? 1u : 0u) << (8 * e);
        }
        flgw[m] = f;   // byte index m*4+e == k*8 + w
    }
    __syncthreads();
    {   // per-segment min of g = hs - k^2 (0 or ~1e18)
        int s = t >> 3, w = t & 7;
        const float* hp = &hs[w * HROW + s * 8];
        float4 A = *reinterpret_cast<const float4*>(hp);
        float4 B = *reinterpret_cast<const float4*>(hp + 4);
        int k0 = s * 8;
        float m0 = fminf(fminf(A.x - (float)(k0 * k0), A.y - (float)((k0 + 1) * (k0 + 1))),
                         A.z - (float)((k0 + 2) * (k0 + 2)));
        float m1 = fminf(fminf(A.w - (float)((k0 + 3) * (k0 + 3)), B.x - (float)((k0 + 4) * (k0 + 4))),
                         B.y - (float)((k0 + 5) * (k0 + 5)));
        float m2 = fminf(B.z - (float)((k0 + 6) * (k0 + 6)), B.w - (float)((k0 + 7) * (k0 + 7)));
        smin[t] = fminf(fminf(m0, m1), m2);  // t == s*8+w
    }
    __syncthreads();

    int w = t & 7, q = t >> 3;
    int i0 = q * 8;
    float best[8], neg2i[8], ifl[8];
#pragma unroll
    for (int j = 0; j < 8; ++j) {
        best[j] = BIG;
        ifl[j] = (float)(i0 + j);
        neg2i[j] = (float)(-2 * (i0 + j));
    }
    eval_ring(&hs[w * HROW], &smin[w], q, best, neg2i, ifl);

    const unsigned char* flgb = reinterpret_cast<const unsigned char*>(flgw);
    float wgf = (float)(w0 + w);
    float* ob = ws + (size_t)b * PLANE + w0 + w;
#pragma unroll
    for (int j = 0; j < 8; ++j) {
        float v = fmaf(ifl[j], ifl[j], best[j]);   // exact d^2 after H
        float v2 = fmaf(wgf, wgf, v);              // fold W-pass +k^2 (exact)
        unsigned int bits = __float_as_uint(v2) |
                            ((unsigned int)flgb[(i0 + j) * TWB + w] << 31);
        ob[(size_t)(i0 + j) * NW] = __uint_as_float(bits);
    }
}

// ---------------------------------------------------------------------------
// K_wb: SECOND kernel = W min-plus + B min-plus + sqrt + NaN, fused per-h.
// Block = one h: stage all 16 b-rows (w-major) into hs[16][516], strip NaN
// sign flags; W eval (2 jobs/thread) into regs; write back; B min-plus per
// w-column (16 outputs x 16 candidates, conflict-free stride-516 reads);
// sqrt + NaN mask; coalesced stores. Grid 512 blocks. No grid sync anywhere.
// ---------------------------------------------------------------------------
__global__ __launch_bounds__(512, 4) void k_pass_wb(const float* __restrict__ ws,
                                                    float* __restrict__ out) {
    __shared__ float hs[NB * HROW];          // 33 KB
    __shared__ unsigned int flgw[NB * NW / 4];  // 8 KB (flag byte per (b,w))
    int t = threadIdx.x;
    int h = blockIdx.x;

    for (int m = t; m < 2048; m += 512) {
        int line = m >> 7;            // b
        int k4 = (m & 127) * 4;       // w base
        float4 v = *reinterpret_cast<const float4*>(
            ws + (size_t)line * PLANE + (size_t)h * NW + k4);
        unsigned int u0 = __float_as_uint(v.x), u1 = __float_as_uint(v.y);
        unsigned int u2 = __float_as_uint(v.z), u3 = __float_as_uint(v.w);
        flgw[m] = (u0 >> 31) | ((u1 >> 31) << 8) |
                  ((u2 >> 31) << 16) | ((u3 >> 31) << 24);
        float4 o;
        o.x = __uint_as_float(u0 & 0x7fffffffu);
        o.y = __uint_as_float(u1 & 0x7fffffffu);
        o.z = __uint_as_float(u2 & 0x7fffffffu);
        o.w = __uint_as_float(u3 & 0x7fffffffu);
        *reinterpret_cast<float4*>(&hs[line * HROW + k4]) = o;
    }
    __syncthreads();

    // ---- W min-plus: 2 jobs/thread, results in registers ----
    int lineA = t >> 6;          // job A: j2 = t
    int qA = t & 63;
    int lineB = lineA + 8;       // job B: j2 = t + 512
    int qB = qA;
    float resA[8], resB[8];
    {
        int i0 = qA * 8;
        float best[8], neg2i[8], ifl[8];
#pragma unroll
        for (int j = 0; j < 8; ++j) {
            best[j] = BIG;
            ifl[j] = (float)(i0 + j);
            neg2i[j] = (float)(-2 * (i0 + j));
        }
        eval_window(&hs[lineA * HROW], qA, best, neg2i, ifl);
#pragma unroll
        for (int j = 0; j < 8; ++j) resA[j] = fmaf(ifl[j], ifl[j], best[j]);
    }
    {
        int i0 = qB * 8;
        float best[8], neg2i[8], ifl[8];
#pragma unroll
        for (int j = 0; j < 8; ++j) {
            best[j] = BIG;
            ifl[j] = (float)(i0 + j);
            neg2i[j] = (float)(-2 * (i0 + j));
        }
        eval_window(&hs[lineB * HROW], qB, best, neg2i, ifl);
#pragma unroll
        for (int j = 0; j < 8; ++j) resB[j] = fmaf(ifl[j], ifl[j], best[j]);
    }
    __syncthreads();
#pragma unroll
    for (int j = 0; j < 8; ++j) hs[lineA * HROW + qA * 8 + j] = resA[j];
#pragma unroll
    for (int j = 0; j < 8; ++j) hs[lineB * HROW + qB * 8 + j] = resB[j];
    __syncthreads();

    // ---- B min-plus per w-column (t == w), sqrt + NaN, store ----
    const unsigned char* flgb = reinterpret_cast<const unsigned char*>(flgw);
    float d2c[NB];
#pragma unroll
    for (int b = 0; b < NB; ++b) d2c[b] = hs[b * HROW + t];  // 2 lanes/bank: free
#pragma unroll
    for (int bp = 0; bp < NB; ++bp) {
        float mm = BIG;
#pragma unroll
        for (int b = 0; b < NB; ++b) {
            float db = (float)((bp - b) * (bp - b));
            mm = fminf(mm, db + d2c[b]);   // exact int (< 2^24) or absorbed 1e18
        }
        float sq = sqrtf(mm);
        float o = flgb[bp * NW + t] ? __builtin_nanf("") : sq;
        out[(size_t)bp * PLANE + (size_t)h * NW + t] = o;
    }
}

extern "C" void kernel_launch(void* const* d_in, const int* in_sizes, int n_in,
                              void* d_out, int out_size, void* d_ws, size_t ws_size,
                              hipStream_t stream) {
    (void)in_sizes; (void)n_in; (void)out_size; (void)ws_size;
    const float* x = (const float*)d_in[0];
    float* out = (float*)d_out;
    float* ws = (float*)d_ws;  // 16.8 MB f32 intermediate (d^2 after H, +w^2)

    // K_h: min-plus along H on indicator (x -> ws), NaN flag in sign bit
    k_pass_h<<<dim3(NW / TWB, NB), 512, 0, stream>>>(x, ws);
    // K_wb: W min-plus + B min-plus + sqrt + NaN (ws -> out), per-h blocks
    k_pass_wb<<<dim3(NH), 512, 0, stream>>>(ws, out);
}

// Round 14
// 38.638 us; speedup vs baseline: 1.3691x; 1.3691x over previous
//
#include <hip/hip_runtime.h>
#include <math.h>
#include <stdint.h>

#define NB 16
#define NH 512
#define NW 512
#define PLANE (NH * NW)
#define INF2 1.0e18f   // == fl(1e9f*1e9f), matches reference rounding
#define BIG 3.0e38f
#define NSEG 64        // 512 / 8
#define HROW 516       // LDS row stride (floats)

// ---------------------------------------------------------------------------
// eval_seg / eval_window: R11's proven exact min-plus (ints < 2^24 exact;
// INF2 absorbs shifts).
// ---------------------------------------------------------------------------
__device__ __forceinline__ void eval_seg(const float* __restrict__ hrow,
                                         int ss, float* best,
                                         const float* neg2i) {
    const float* hp = hrow + ss * 8;
    float4 A = *reinterpret_cast<const float4*>(hp);
    float4 B = *reinterpret_cast<const float4*>(hp + 4);
    float s8f = (float)(ss * 8);
#pragma unroll
    for (int j = 0; j < 8; ++j) {
        float n2 = neg2i[j];
        float c0 = fmaf(n2, s8f, A.x);
        float c1 = fmaf(n2, s8f + 1.0f, A.y);
        float c2 = fmaf(n2, s8f + 2.0f, A.z);
        float c3 = fmaf(n2, s8f + 3.0f, A.w);
        float c4 = fmaf(n2, s8f + 4.0f, B.x);
        float c5 = fmaf(n2, s8f + 5.0f, B.y);
        float c6 = fmaf(n2, s8f + 6.0f, B.z);
        float c7 = fmaf(n2, s8f + 7.0f, B.w);
        float bb = fminf(fminf(best[j], c0), c1);
        bb = fminf(fminf(bb, c2), c3);
        bb = fminf(fminf(bb, c4), c5);
        bb = fminf(fminf(bb, c6), c7);
        best[j] = bb;
    }
}

__device__ __forceinline__ void eval_window(const float* __restrict__ hrow,
                                            int q, float* best,
                                            const float* neg2i,
                                            const float* ifl) {
    int s_lo0 = (q > 0) ? q - 1 : 0;
    int s_hi0 = (q < NSEG - 1) ? q + 1 : NSEG - 1;
    for (int ss = s_lo0; ss <= s_hi0; ++ss) eval_seg(hrow, ss, best, neg2i);
    float t0 = fmaf(ifl[0], ifl[0], best[0]);
    float t1 = fmaf(ifl[1], ifl[1], best[1]);
    float t2 = fmaf(ifl[2], ifl[2], best[2]);
    float t3 = fmaf(ifl[3], ifl[3], best[3]);
    float t4 = fmaf(ifl[4], ifl[4], best[4]);
    float t5 = fmaf(ifl[5], ifl[5], best[5]);
    float t6 = fmaf(ifl[6], ifl[6], best[6]);
    float t7 = fmaf(ifl[7], ifl[7], best[7]);
    float m = fmaxf(fmaxf(t0, t1), t2);
    m = fmaxf(fmaxf(m, t3), t4);
    m = fmaxf(fmaxf(m, t5), t6);
    float bmax = fmaxf(m, t7);
    int sw = (int)sqrtf(bmax) + 1;
    int i0 = q * 8;
    int s_lo = (i0 - sw) >> 3;
    int s_hi = (i0 + 7 + sw) >> 3;
    if (s_lo < 0) s_lo = 0;
    if (s_hi > NSEG - 1) s_hi = NSEG - 1;
    for (int ss = s_lo; ss <= s_hi; ++ss) {
        if (ss >= s_lo0 && ss <= s_hi0) continue;
        eval_seg(hrow, ss, best, neg2i);
    }
}

// ---------------------------------------------------------------------------
// K_a: exact 1D nearest-zero distance along H per (b,w) column, O(1)/elem
// chunked scan. Block = (b, 8-wide w tile), 512 thr; thread (w=t&7, q=t>>3)
// owns h-chunk [8q, 8q+8). Internal fwd/bwd runs + per-chunk first/last zero
// summaries; cross-chunk via prefix-max(Rz)/suffix-min(Lz). All int -> exact.
// Output u16 = d (0..511; 1023 = INF) | nan<<15.
// ---------------------------------------------------------------------------
__global__ __launch_bounds__(512, 4) void k_scan_h(const float* __restrict__ x,
                                                   unsigned short* __restrict__ code) {
    __shared__ float hs[8 * HROW];         // indicator 1.0 = zero, [w][h]
    __shared__ unsigned int flgw[1024];    // nan flags, byte idx = h*8 + w
    __shared__ int lza[512], rza[512];     // [q*8 + w]
    int t = threadIdx.x;
    int b = blockIdx.y;
    int w0 = blockIdx.x * 8;
    const float* xb = x + (size_t)b * PLANE + w0;

    for (int m = t; m < 1024; m += 512) {
        int k = m >> 1, half = m & 1;
        float4 v = *reinterpret_cast<const float4*>(xb + (size_t)k * NW + half * 4);
        unsigned int f = 0;
#pragma unroll
        for (int e = 0; e < 4; ++e) {
            float val = (&v.x)[e];
            hs[(half * 4 + e) * HROW + k] = (val == 0.0f) ? 1.0f : 0.0f;
            f |= (isnan(val) ? 1u : 0u) << (8 * e);
        }
        flgw[m] = f;  // byte m*4+e == k*8 + w
    }
    __syncthreads();

    int w = t & 7, q = t >> 3;
    int base = w * HROW + q * 8;
    float4 A = *reinterpret_cast<const float4*>(&hs[base]);
    float4 Bv = *reinterpret_cast<const float4*>(&hs[base + 4]);
    unsigned int mask = 0;
#pragma unroll
    for (int e = 0; e < 4; ++e) mask |= ((&A.x)[e] == 1.0f ? 1u : 0u) << e;
#pragma unroll
    for (int e = 0; e < 4; ++e) mask |= ((&Bv.x)[e] == 1.0f ? 1u : 0u) << (e + 4);
    lza[q * 8 + w] = mask ? (q * 8 + __ffs(mask) - 1) : (1 << 20);
    rza[q * 8 + w] = mask ? (q * 8 + 31 - __clz(mask)) : -(1 << 20);

    int fwd[8], bwd[8];
    int run = 1 << 20;
#pragma unroll
    for (int e = 0; e < 8; ++e) { run = ((mask >> e) & 1) ? 0 : run + 1; fwd[e] = run; }
    run = 1 << 20;
#pragma unroll
    for (int e = 7; e >= 0; --e) { run = ((mask >> e) & 1) ? 0 : run + 1; bwd[e] = run; }
    __syncthreads();

    int pmax = -(1 << 20);
    for (int c = 0; c < q; ++c) pmax = max(pmax, rza[c * 8 + w]);
    int smin = 1 << 20;
    for (int c = q + 1; c < 64; ++c) smin = min(smin, lza[c * 8 + w]);

    const unsigned char* flgb = reinterpret_cast<const unsigned char*>(flgw);
#pragma unroll
    for (int e = 0; e < 8; ++e) {
        int i = q * 8 + e;
        int d = min(min(fwd[e], bwd[e]), min(i - pmax, smin - i));
        if (d > 511) d = 1023;  // no zero anywhere in column -> INF sentinel
        unsigned short o = (unsigned short)(d | ((flgb[i * 8 + w] & 1) << 15));
        code[(size_t)b * PLANE + (size_t)i * NW + w0 + w] = o;
    }
}

// ---------------------------------------------------------------------------
// K_wb: per-h block (512 blocks x 1024 thr = 2 blocks/CU = 32 waves/CU).
// Stage: decode u16 -> hs[b][w] = d^2 + w^2 (exact int) or INF2; nan -> flg.
// W min-plus (window eval, 1 job/thread) -> write back to hs.
// B min-plus per w-column (16 cand, exact) + sqrt + NaN, coalesced stores.
// ---------------------------------------------------------------------------
__global__ __launch_bounds__(1024, 2) void k_wb(const unsigned short* __restrict__ code,
                                                float* __restrict__ out) {
    __shared__ float hs[NB * HROW];          // 33 KB
    __shared__ unsigned char flg[NB * NW];   // 8 KB
    int t = threadIdx.x;
    int h = blockIdx.x;

    const unsigned int* cp = reinterpret_cast<const unsigned int*>(code);
    for (int m = t; m < NB * NW / 2; m += 1024) {
        int b = m >> 8;       // 256 u32 per (b,h) row
        int wp = m & 255;
        unsigned int v = cp[((size_t)b * PLANE + (size_t)h * NW) / 2 + wp];
        int wa = wp * 2;
        int dl0 = v & 1023, dl1 = (v >> 16) & 1023;
        unsigned short fpair = (unsigned short)(((v >> 15) & 1u) | (((v >> 31) & 1u) << 8));
        *reinterpret_cast<unsigned short*>(&flg[b * NW + wa]) = fpair;
        hs[b * HROW + wa] = (dl0 == 1023) ? INF2 : (float)(dl0 * dl0 + wa * wa);
        hs[b * HROW + wa + 1] = (dl1 == 1023) ? INF2 : (float)(dl1 * dl1 + (wa + 1) * (wa + 1));
    }
    __syncthreads();

    // ---- W min-plus: thread t -> (line = t>>6, q = t&63) ----
    int line = t >> 6, q = t & 63;
    int i0 = q * 8;
    float res[8];
    {
        float best[8], neg2i[8], ifl[8];
#pragma unroll
        for (int j = 0; j < 8; ++j) {
            best[j] = BIG;
            ifl[j] = (float)(i0 + j);
            neg2i[j] = (float)(-2 * (i0 + j));
        }
        eval_window(&hs[line * HROW], q, best, neg2i, ifl);
#pragma unroll
        for (int j = 0; j < 8; ++j) res[j] = fmaf(ifl[j], ifl[j], best[j]);  // exact
    }
    __syncthreads();
#pragma unroll
    for (int j = 0; j < 8; ++j) hs[line * HROW + i0 + j] = res[j];
    __syncthreads();

    // ---- B min-plus per w-column + sqrt + NaN ----
    int w = t & 511, g = t >> 9;
    float d2c[NB];
#pragma unroll
    for (int b2 = 0; b2 < NB; ++b2) d2c[b2] = hs[b2 * HROW + w];
#pragma unroll
    for (int j = 0; j < 8; ++j) {
        int bp = g * 8 + j;
        float mm = BIG;
#pragma unroll
        for (int b2 = 0; b2 < NB; ++b2) {
            float db = (float)((bp - b2) * (bp - b2));
            mm = fminf(mm, db + d2c[b2]);  // exact int or absorbed 1e18
        }
        float sq = sqrtf(mm);
        float o = flg[bp * NW + w] ? __builtin_nanf("") : sq;
        out[(size_t)bp * PLANE + (size_t)h * NW + w] = o;
    }
}

extern "C" void kernel_launch(void* const* d_in, const int* in_sizes, int n_in,
                              void* d_out, int out_size, void* d_ws, size_t ws_size,
                              hipStream_t stream) {
    (void)in_sizes; (void)n_in; (void)out_size; (void)ws_size;
    const float* x = (const float*)d_in[0];
    float* out = (float*)d_out;
    unsigned short* code = (unsigned short*)d_ws;  // 8.4 MB u16 (d_H | nan<<15)

    // K_a: 1D nearest-zero scan along H (x -> code)
    k_scan_h<<<dim3(NW / 8, NB), 512, 0, stream>>>(x, code);
    // K_wb: W min-plus + B min-plus + sqrt + NaN (code -> out)
    k_wb<<<dim3(NH), 1024, 0, stream>>>(code, out);
}

// Round 15
// 37.939 us; speedup vs baseline: 1.3944x; 1.0184x over previous
//
#include <hip/hip_runtime.h>
#include <math.h>
#include <stdint.h>

#define NB 16
#define NH 512
#define NW 512
#define PLANE (NH * NW)
#define INF2 1.0e18f   // == fl(1e9f*1e9f): matches reference d*d exactly
#define BIG 3.0e38f
#define NSEG 64        // 512 / 8
#define HROW 516       // LDS row stride (floats)

// ---------------------------------------------------------------------------
// eval_seg / eval_window: proven exact min-plus (R11). candidate =
// fma(-2i, k, h[k]); all finite values exact ints < 2^24; INF2 absorbs shifts.
// ---------------------------------------------------------------------------
__device__ __forceinline__ void eval_seg(const float* __restrict__ hrow,
                                         int ss, float* best,
                                         const float* neg2i) {
    const float* hp = hrow + ss * 8;
    float4 A = *reinterpret_cast<const float4*>(hp);
    float4 B = *reinterpret_cast<const float4*>(hp + 4);
    float s8f = (float)(ss * 8);
#pragma unroll
    for (int j = 0; j < 8; ++j) {
        float n2 = neg2i[j];
        float c0 = fmaf(n2, s8f, A.x);
        float c1 = fmaf(n2, s8f + 1.0f, A.y);
        float c2 = fmaf(n2, s8f + 2.0f, A.z);
        float c3 = fmaf(n2, s8f + 3.0f, A.w);
        float c4 = fmaf(n2, s8f + 4.0f, B.x);
        float c5 = fmaf(n2, s8f + 5.0f, B.y);
        float c6 = fmaf(n2, s8f + 6.0f, B.z);
        float c7 = fmaf(n2, s8f + 7.0f, B.w);
        float bb = fminf(fminf(best[j], c0), c1);
        bb = fminf(fminf(bb, c2), c3);
        bb = fminf(fminf(bb, c4), c5);
        bb = fminf(fminf(bb, c6), c7);
        best[j] = bb;
    }
}

__device__ __forceinline__ void eval_window(const float* __restrict__ hrow,
                                            int q, float* best,
                                            const float* neg2i,
                                            const float* ifl) {
    int s_lo0 = (q > 0) ? q - 1 : 0;
    int s_hi0 = (q < NSEG - 1) ? q + 1 : NSEG - 1;
    for (int ss = s_lo0; ss <= s_hi0; ++ss) eval_seg(hrow, ss, best, neg2i);
    float t0 = fmaf(ifl[0], ifl[0], best[0]);
    float t1 = fmaf(ifl[1], ifl[1], best[1]);
    float t2 = fmaf(ifl[2], ifl[2], best[2]);
    float t3 = fmaf(ifl[3], ifl[3], best[3]);
    float t4 = fmaf(ifl[4], ifl[4], best[4]);
    float t5 = fmaf(ifl[5], ifl[5], best[5]);
    float t6 = fmaf(ifl[6], ifl[6], best[6]);
    float t7 = fmaf(ifl[7], ifl[7], best[7]);
    float m = fmaxf(fmaxf(t0, t1), t2);
    m = fmaxf(fmaxf(m, t3), t4);
    m = fmaxf(fmaxf(m, t5), t6);
    float bmax = fmaxf(m, t7);
    int sw = (int)sqrtf(bmax) + 1;      // conservative window radius
    int i0 = q * 8;
    int s_lo = (i0 - sw) >> 3;
    int s_hi = (i0 + 7 + sw) >> 3;
    if (s_lo < 0) s_lo = 0;
    if (s_hi > NSEG - 1) s_hi = NSEG - 1;
    for (int ss = s_lo; ss <= s_hi; ++ss) {
        if (ss >= s_lo0 && ss <= s_hi0) continue;
        eval_seg(hrow, ss, best, neg2i);
    }
}

// ---------------------------------------------------------------------------
// K_a: exact 1D nearest-zero distance along H. Block = (b, 8 w-cols), 512
// thr; ONE WAVE PER COLUMN (w = t>>6, lane q = chunk of 8 h). Chunk-internal
// fwd/bwd runs; cross-chunk via wave-level exclusive prefix-max (last zero
// below) and suffix-min (first zero above) in 6 shfl steps each. All int ->
// exact. Output u16 d (0..511; 1023 = no zero in column). No NaN plumbing.
// ---------------------------------------------------------------------------
__global__ __launch_bounds__(512, 4) void k_scan_h(const float* __restrict__ x,
                                                   unsigned short* __restrict__ code) {
    __shared__ float ind[8 * HROW];           // [w][h] indicator, 16.5 KB
    __shared__ unsigned short d16[8 * 520];   // [w][h] results, 8.1 KB
    int t = threadIdx.x;
    int b = blockIdx.y;
    int w0 = blockIdx.x * 8;
    const float* xb = x + (size_t)b * PLANE + w0;

    for (int m = t; m < 1024; m += 512) {
        int h = m >> 1, half = m & 1;
        float4 v = *reinterpret_cast<const float4*>(xb + (size_t)h * NW + half * 4);
#pragma unroll
        for (int e = 0; e < 4; ++e)
            ind[(half * 4 + e) * HROW + h] = ((&v.x)[e] == 0.0f) ? 1.0f : 0.0f;
    }
    __syncthreads();

    int w = t >> 6, q = t & 63;               // one wave = one column
    const float* col = &ind[w * HROW + q * 8];
    float4 A = *reinterpret_cast<const float4*>(col);
    float4 Bv = *reinterpret_cast<const float4*>(col + 4);
    unsigned int mask = 0;
#pragma unroll
    for (int e = 0; e < 4; ++e) mask |= (((&A.x)[e] == 1.0f) ? 1u : 0u) << e;
#pragma unroll
    for (int e = 0; e < 4; ++e) mask |= (((&Bv.x)[e] == 1.0f) ? 1u : 0u) << (e + 4);

    int fwd[8], bwd[8];
    int run = 1 << 20;
#pragma unroll
    for (int e = 0; e < 8; ++e) { run = ((mask >> e) & 1) ? 0 : run + 1; fwd[e] = run; }
    run = 1 << 20;
#pragma unroll
    for (int e = 7; e >= 0; --e) { run = ((mask >> e) & 1) ? 0 : run + 1; bwd[e] = run; }

    int lz = mask ? (q * 8 + __ffs(mask) - 1) : (1 << 20);    // first zero in chunk
    int rz = mask ? (q * 8 + 31 - __clz(mask)) : -(1 << 20);  // last zero in chunk

    // exclusive prefix-max of rz over lanes (last zero strictly below chunk)
    int pm = rz;
#pragma unroll
    for (int d = 1; d < 64; d <<= 1) {
        int o = __shfl_up(pm, d);
        if (q >= d) pm = max(pm, o);
    }
    int pmax = __shfl_up(pm, 1);
    if (q == 0) pmax = -(1 << 20);
    // exclusive suffix-min of lz (first zero strictly above chunk)
    int sm = lz;
#pragma unroll
    for (int d = 1; d < 64; d <<= 1) {
        int o = __shfl_down(sm, d);
        if (q + d < 64) sm = min(sm, o);
    }
    int smin = __shfl_down(sm, 1);
    if (q == 63) smin = 1 << 20;

    unsigned int dv[8];
#pragma unroll
    for (int e = 0; e < 8; ++e) {
        int i = q * 8 + e;
        int dd = min(min(fwd[e], bwd[e]), min(i - pmax, smin - i));
        dv[e] = (unsigned int)((dd > 511) ? 1023 : dd);
    }
    uint4 pk;
    pk.x = dv[0] | (dv[1] << 16);
    pk.y = dv[2] | (dv[3] << 16);
    pk.z = dv[4] | (dv[5] << 16);
    pk.w = dv[6] | (dv[7] << 16);
    *reinterpret_cast<uint4*>(&d16[w * 520 + q * 8]) = pk;
    __syncthreads();

    // write-out: thread t = one h-row, 8 u16 = 16 B per row
    {
        int h = t;
        unsigned int r[4];
#pragma unroll
        for (int p = 0; p < 4; ++p) {
            unsigned int lo = d16[(2 * p) * 520 + h];
            unsigned int hi = d16[(2 * p + 1) * 520 + h];
            r[p] = lo | (hi << 16);
        }
        uint4 o; o.x = r[0]; o.y = r[1]; o.z = r[2]; o.w = r[3];
        *reinterpret_cast<uint4*>(&code[(size_t)b * PLANE + (size_t)h * NW + w0]) = o;
    }
}

// ---------------------------------------------------------------------------
// K_wb: per-h block, 1024 thr, (1024,2) -> 2 blocks/CU = 32 waves/CU.
// Stage: decode u16 -> hs[b][w] = d^2 + w^2 (exact) or INF2 (33 KB LDS).
// W min-plus: 1 job/thread (line = t>>6, q = t&63), window eval.
// Write-back; B min-plus 2 threads/column (8 outputs each, 16 candidates).
// Epilogue: sqrt + NaN from re-reading x (no flag plumbing).
// ---------------------------------------------------------------------------
__global__ __launch_bounds__(1024, 2) void k_wb(const unsigned short* __restrict__ code,
                                                const float* __restrict__ x,
                                                float* __restrict__ out) {
    __shared__ float hs[NB * HROW];   // 33 KB
    int t = threadIdx.x;
    int h = blockIdx.x;

    const unsigned int* cp = reinterpret_cast<const unsigned int*>(code);
    for (int m = t; m < NB * NW / 2; m += 1024) {
        int b = m >> 8, wp = m & 255;
        unsigned int v = cp[((size_t)b * PLANE + (size_t)h * NW) / 2 + wp];
        int wa = wp * 2;
        int d0 = v & 0xFFFF, d1 = v >> 16;
        hs[b * HROW + wa] = (d0 == 1023) ? INF2 : (float)(d0 * d0 + wa * wa);
        hs[b * HROW + wa + 1] = (d1 == 1023) ? INF2 : (float)(d1 * d1 + (wa + 1) * (wa + 1));
    }
    __syncthreads();

    // ---- W min-plus (1 job/thread), results to regs ----
    int line = t >> 6, q = t & 63;
    int i0 = q * 8;
    float res[8];
    {
        float best[8], neg2i[8], ifl[8];
#pragma unroll
        for (int j = 0; j < 8; ++j) {
            best[j] = BIG;
            ifl[j] = (float)(i0 + j);
            neg2i[j] = (float)(-2 * (i0 + j));
        }
        eval_window(&hs[line * HROW], q, best, neg2i, ifl);
#pragma unroll
        for (int j = 0; j < 8; ++j) res[j] = fmaf(ifl[j], ifl[j], best[j]);  // exact
    }
    __syncthreads();
#pragma unroll
    for (int j = 0; j < 8; ++j) hs[line * HROW + i0 + j] = res[j];
    __syncthreads();

    // ---- B min-plus: 2 threads per w-column, 8 outputs each ----
    int w = t & 511, g = t >> 9;
    float d2c[NB];
#pragma unroll
    for (int bb = 0; bb < NB; ++bb) d2c[bb] = hs[bb * HROW + w];
#pragma unroll
    for (int j = 0; j < 8; ++j) {
        int bp = g * 8 + j;
        float mm = BIG;
#pragma unroll
        for (int bb = 0; bb < NB; ++bb) {
            float db = (float)((bp - bb) * (bp - bb));
            mm = fminf(mm, db + d2c[bb]);   // exact int or absorbed INF2
        }
        size_t idx = (size_t)bp * PLANE + (size_t)h * NW + w;
        float xv = x[idx];
        out[idx] = isnan(xv) ? __builtin_nanf("") : sqrtf(mm);
    }
}

extern "C" void kernel_launch(void* const* d_in, const int* in_sizes, int n_in,
                              void* d_out, int out_size, void* d_ws, size_t ws_size,
                              hipStream_t stream) {
    (void)in_sizes; (void)n_in; (void)out_size; (void)ws_size;
    const float* x = (const float*)d_in[0];
    float* out = (float*)d_out;
    unsigned short* code = (unsigned short*)d_ws;  // 8.4 MB u16 (d along H)

    // K_a: 1D nearest-zero scan along H (x -> code), wave-per-column
    k_scan_h<<<dim3(NW / 8, NB), 512, 0, stream>>>(x, code);
    // K_wb: W min-plus + B min-plus + sqrt + NaN (code, x -> out)
    k_wb<<<dim3(NH), 1024, 0, stream>>>(code, x, out);
}